// Round 1
// baseline (116.638 us; speedup 1.0000x reference)
//
#include <hip/hip_runtime.h>
#include <hip/hip_bf16.h>

// GlobalEmbedder: packed-graph MHA (128 graphs x 32 nodes, D=128, H=4, K=32)
// k1: fused QKV+attention per (graph,head)  -> attout bf16 [4096][128] in ws
// k2: Wo [128][4096] fp32 -> WoT [4096][128] bf16 in ws (B-operand layout)
// k3: out = attout @ Wo + bo, bf16 MFMA, fp32 out [4096][4096] (64MB, HBM-write bound)

typedef __attribute__((ext_vector_type(4))) float f32x4;
typedef __attribute__((ext_vector_type(8))) short s16x8;
typedef __attribute__((ext_vector_type(4))) short s16x4;
typedef __attribute__((ext_vector_type(8))) __bf16 bf16x8;

static __device__ __forceinline__ short f2bf(float f) {
  union { float f; unsigned u; } v; v.f = f;
  unsigned r = v.u + 0x7fffu + ((v.u >> 16) & 1u);  // RNE
  return (short)(r >> 16);
}

static __device__ __forceinline__ f32x4 mfma16(s16x8 a, s16x8 b, f32x4 c) {
  return __builtin_amdgcn_mfma_f32_16x16x32_bf16(
      __builtin_bit_cast(bf16x8, a), __builtin_bit_cast(bf16x8, b), c, 0, 0, 0);
}

// ---------------------------------------------------------------- kernel 1
// grid (128 graphs, 4 heads), 64 threads (one wave).
__global__ __launch_bounds__(64) void k1_qkv_attn(
    const float* __restrict__ nodes,
    const float* __restrict__ Wq, const float* __restrict__ bq,
    const float* __restrict__ Wk, const float* __restrict__ bk,
    const float* __restrict__ Wv, const float* __restrict__ bv,
    unsigned short* __restrict__ attout)
{
  const int g = blockIdx.x;
  const int h = blockIdx.y;
  const int lane = threadIdx.x;
  const int l15 = lane & 15;
  const int qd = lane >> 4;

  __shared__ alignas(16) short sN[32][136];   // nodes_g bf16, padded
  __shared__ alignas(16) short sQ[32][40];    // q[m][c] (pre-scaled by 1/sqrt(32))
  __shared__ alignas(16) short sK[32][40];    // k[m'][c]
  __shared__ alignas(16) short sVT[32][40];   // v^T[n][m]
  __shared__ alignas(16) short sP[32][40];    // softmax probs [m][m']

  // ---- stage nodes (fp32 -> bf16)
  const float* ng = nodes + g * 32 * 128;
  #pragma unroll
  for (int i = 0; i < 16; ++i) {
    int f4  = i * 64 + lane;       // 0..1023 float4 chunks
    int row = f4 >> 5;             // 32 float4 per 128-wide row
    int c4  = (f4 & 31) << 2;
    float4 v = *(const float4*)(ng + row * 128 + c4);
    s16x4 p;
    p[0] = f2bf(v.x); p[1] = f2bf(v.y); p[2] = f2bf(v.z); p[3] = f2bf(v.w);
    *(s16x4*)&sN[row][c4] = p;
  }
  __syncthreads();

  // A-fragments of nodes (shared by q/k/v): A[m=l15][k contiguous 8]
  s16x8 afrag[2][4];
  #pragma unroll
  for (int mt = 0; mt < 2; ++mt)
    #pragma unroll
    for (int kk = 0; kk < 4; ++kk)
      afrag[mt][kk] = *(const s16x8*)&sN[mt * 16 + l15][kk * 32 + qd * 8];

  const float* Wm[3] = {Wq, Wk, Wv};
  const float* Bm[3] = {bq, bk, bv};

  // ---- QKV projections via MFMA (M=32,N=32,K=128 per head)
  #pragma unroll
  for (int m3 = 0; m3 < 3; ++m3) {
    f32x4 acc[2][2];
    f32x4 zero = {0.f, 0.f, 0.f, 0.f};
    acc[0][0] = zero; acc[0][1] = zero; acc[1][0] = zero; acc[1][1] = zero;
    const float* W = Wm[m3];
    #pragma unroll
    for (int kk = 0; kk < 4; ++kk) {
      s16x8 bfr[2];
      #pragma unroll
      for (int nt = 0; nt < 2; ++nt) {
        // B[k=d][n=head col]: W[d*128 + h*32 + c], d = kk*32+qd*8+j
        const float* src = W + (kk * 32 + qd * 8) * 128 + h * 32 + nt * 16 + l15;
        s16x8 e;
        #pragma unroll
        for (int j = 0; j < 8; ++j) e[j] = f2bf(src[j * 128]);
        bfr[nt] = e;
      }
      #pragma unroll
      for (int mt = 0; mt < 2; ++mt)
        #pragma unroll
        for (int nt = 0; nt < 2; ++nt)
          acc[mt][nt] = mfma16(afrag[mt][kk], bfr[nt], acc[mt][nt]);
    }
    float b0 = Bm[m3][h * 32 + l15];
    float b1 = Bm[m3][h * 32 + 16 + l15];
    #pragma unroll
    for (int mt = 0; mt < 2; ++mt)
      #pragma unroll
      for (int nt = 0; nt < 2; ++nt) {
        float bb = nt ? b1 : b0;
        #pragma unroll
        for (int r = 0; r < 4; ++r) {
          int m = mt * 16 + qd * 4 + r;       // C/D: row=quad*4+reg
          int c = nt * 16 + l15;              //      col=lane&15
          float val = acc[mt][nt][r] + bb;
          if (m3 == 0)      sQ[m][c]  = f2bf(val * 0.17677669529663687f); // 1/sqrt(32)
          else if (m3 == 1) sK[m][c]  = f2bf(val);
          else              sVT[c][m] = f2bf(val);   // transposed for PV B-operand
        }
      }
  }
  __syncthreads();

  // ---- scores = q @ k^T  (M=32,N=32,K=32 -> 4 MFMA)
  s16x8 qf[2], kf[2];
  #pragma unroll
  for (int mt = 0; mt < 2; ++mt) qf[mt] = *(const s16x8*)&sQ[mt * 16 + l15][qd * 8];
  #pragma unroll
  for (int nt = 0; nt < 2; ++nt) kf[nt] = *(const s16x8*)&sK[nt * 16 + l15][qd * 8];
  f32x4 sacc[2][2];
  {
    f32x4 zero = {0.f, 0.f, 0.f, 0.f};
    #pragma unroll
    for (int mt = 0; mt < 2; ++mt)
      #pragma unroll
      for (int nt = 0; nt < 2; ++nt)
        sacc[mt][nt] = mfma16(qf[mt], kf[nt], zero);
  }

  // ---- softmax over 32 cols (row r lives in one 16-lane quad group, 2 acc tiles)
  #pragma unroll
  for (int mt = 0; mt < 2; ++mt)
    #pragma unroll
    for (int r = 0; r < 4; ++r) {
      float a0 = sacc[mt][0][r], a1 = sacc[mt][1][r];
      float mx = fmaxf(a0, a1);
      mx = fmaxf(mx, __shfl_xor(mx, 1, 64));
      mx = fmaxf(mx, __shfl_xor(mx, 2, 64));
      mx = fmaxf(mx, __shfl_xor(mx, 4, 64));
      mx = fmaxf(mx, __shfl_xor(mx, 8, 64));
      float e0 = __expf(a0 - mx), e1 = __expf(a1 - mx);
      float s = e0 + e1;
      s += __shfl_xor(s, 1, 64);
      s += __shfl_xor(s, 2, 64);
      s += __shfl_xor(s, 4, 64);
      s += __shfl_xor(s, 8, 64);
      float inv = 1.0f / s;
      int m = mt * 16 + qd * 4 + r;
      sP[m][l15]      = f2bf(e0 * inv);
      sP[m][16 + l15] = f2bf(e1 * inv);
    }
  __syncthreads();

  // ---- out = P @ v  (4 MFMA), write attout bf16
  s16x8 pf[2], vf[2];
  #pragma unroll
  for (int mt = 0; mt < 2; ++mt) pf[mt] = *(const s16x8*)&sP[mt * 16 + l15][qd * 8];
  #pragma unroll
  for (int nt = 0; nt < 2; ++nt) vf[nt] = *(const s16x8*)&sVT[nt * 16 + l15][qd * 8];
  f32x4 oacc[2][2];
  {
    f32x4 zero = {0.f, 0.f, 0.f, 0.f};
    #pragma unroll
    for (int mt = 0; mt < 2; ++mt)
      #pragma unroll
      for (int nt = 0; nt < 2; ++nt)
        oacc[mt][nt] = mfma16(pf[mt], vf[nt], zero);
  }
  unsigned short* ao = attout + (g * 32) * 128 + h * 32;
  #pragma unroll
  for (int mt = 0; mt < 2; ++mt)
    #pragma unroll
    for (int nt = 0; nt < 2; ++nt)
      #pragma unroll
      for (int r = 0; r < 4; ++r) {
        int m = mt * 16 + qd * 4 + r;
        int c = nt * 16 + l15;
        ao[m * 128 + c] = (unsigned short)f2bf(oacc[mt][nt][r]);
      }
}

// ---------------------------------------------------------------- kernel 2
// Wo [128][4096] fp32 -> WoT [4096][128] bf16. Strided reads are L2-absorbed (2MB src).
__global__ __launch_bounds__(256) void k2_transpose(
    const float* __restrict__ Wo, unsigned short* __restrict__ WoT)
{
  int idx = blockIdx.x * 256 + threadIdx.x;  // 0..524287
  int n = idx >> 7;
  int k = idx & 127;
  WoT[idx] = (unsigned short)f2bf(Wo[k * 4096 + n]);
}

// ---------------------------------------------------------------- kernel 3
// C[4096][4096] = attout[4096][128] @ Wo[128][4096] + bo. 128x128 tiles, K=128 whole.
__global__ __launch_bounds__(256) void k3_gemm(
    const unsigned short* __restrict__ A,   // attout bf16 row-major [4096][128]
    const unsigned short* __restrict__ BT,  // WoT bf16 [4096 n][128 k]
    const float* __restrict__ bo,
    float* __restrict__ C)
{
  __shared__ alignas(16) short sA[128][136];
  __shared__ alignas(16) short sB[128][136];
  const int t  = threadIdx.x;
  const int m0 = blockIdx.y << 7;
  const int n0 = blockIdx.x << 7;

  // stage A (rows m0..) and B (rows n0..) tiles: 16B chunks, padded LDS rows
  #pragma unroll
  for (int i = 0; i < 8; ++i) {
    int id  = i * 256 + t;
    int row = id >> 4;
    int ch  = (id & 15) << 3;
    *(s16x8*)&sA[row][ch] = *(const s16x8*)(A  + (m0 + row) * 128 + ch);
    *(s16x8*)&sB[row][ch] = *(const s16x8*)(BT + (n0 + row) * 128 + ch);
  }
  __syncthreads();

  const int w    = t >> 6;
  const int lane = t & 63;
  const int l15  = lane & 15;
  const int qd   = lane >> 4;
  const int wm   = (w >> 1) << 6;   // wave row offset in tile
  const int wn   = (w & 1) << 6;    // wave col offset in tile

  f32x4 acc[4][4];
  {
    f32x4 zero = {0.f, 0.f, 0.f, 0.f};
    #pragma unroll
    for (int i = 0; i < 4; ++i)
      #pragma unroll
      for (int j = 0; j < 4; ++j) acc[i][j] = zero;
  }

  #pragma unroll
  for (int kk = 0; kk < 4; ++kk) {
    s16x8 af[4], bf[4];
    #pragma unroll
    for (int i = 0; i < 4; ++i)
      af[i] = *(const s16x8*)&sA[wm + i * 16 + l15][kk * 32 + qd * 8];
    #pragma unroll
    for (int j = 0; j < 4; ++j)
      bf[j] = *(const s16x8*)&sB[wn + j * 16 + l15][kk * 32 + qd * 8];
    #pragma unroll
    for (int i = 0; i < 4; ++i)
      #pragma unroll
      for (int j = 0; j < 4; ++j)
        acc[i][j] = mfma16(af[i], bf[j], acc[i][j]);
  }

  float bov[4];
  #pragma unroll
  for (int j = 0; j < 4; ++j) bov[j] = bo[n0 + wn + j * 16 + l15];

  #pragma unroll
  for (int i = 0; i < 4; ++i) {
    int rbase = m0 + wm + i * 16 + qd * 4;
    #pragma unroll
    for (int r = 0; r < 4; ++r) {
      float* crow = C + (rbase + r) * 4096 + n0 + wn + l15;
      #pragma unroll
      for (int j = 0; j < 4; ++j)
        crow[j * 16] = acc[i][j][r] + bov[j];
    }
  }
}

// ---------------------------------------------------------------- launch
extern "C" void kernel_launch(void* const* d_in, const int* in_sizes, int n_in,
                              void* d_out, int out_size, void* d_ws, size_t ws_size,
                              hipStream_t stream) {
  const float* nodes = (const float*)d_in[0];
  // d_in[1] = n_node (always 32 per graph in this problem) — segmentation hard-coded
  const float* Wq = (const float*)d_in[2];
  const float* bq = (const float*)d_in[3];
  const float* Wk = (const float*)d_in[4];
  const float* bk = (const float*)d_in[5];
  const float* Wv = (const float*)d_in[6];
  const float* bv = (const float*)d_in[7];
  const float* Wo = (const float*)d_in[8];
  const float* bo = (const float*)d_in[9];
  float* out = (float*)d_out;

  unsigned short* attout = (unsigned short*)d_ws;          // 4096*128 bf16 = 1 MB
  unsigned short* WoT    = attout + 4096 * 128;            // 4096*128 bf16 = 1 MB

  k1_qkv_attn<<<dim3(128, 4), 64, 0, stream>>>(nodes, Wq, bq, Wk, bk, Wv, bv, attout);
  k2_transpose<<<2048, 256, 0, stream>>>(Wo, WoT);
  k3_gemm<<<dim3(32, 32), 256, 0, stream>>>(attout, WoT, bo, out);
}

// Round 2
// 109.208 us; speedup vs baseline: 1.0680x; 1.0680x over previous
//
#include <hip/hip_runtime.h>
#include <hip/hip_bf16.h>

// GlobalEmbedder: packed-graph MHA (128 graphs x 32 nodes, D=128, H=4, K=32)
// k0: transpose+convert ALL weights once:
//     Wq/Wk/Wv [128][128] fp32 -> WqkvT[3][128][128] bf16 (B-fragment layout [n][d])
//     Wo [128][4096] fp32      -> WoT  [4096][128]    bf16
// k1: fused QKV+attention per (graph,head) -> attout bf16 [4096][128]
// k3: out = attout @ Wo + bo, bf16 MFMA, fp32 out [4096][4096] (64MB write-bound)

typedef __attribute__((ext_vector_type(4))) float f32x4;
typedef __attribute__((ext_vector_type(8))) short s16x8;
typedef __attribute__((ext_vector_type(4))) short s16x4;
typedef __attribute__((ext_vector_type(8))) __bf16 bf16x8;

static __device__ __forceinline__ short f2bf(float f) {
  union { float f; unsigned u; } v; v.f = f;
  unsigned r = v.u + 0x7fffu + ((v.u >> 16) & 1u);  // RNE
  return (short)(r >> 16);
}

static __device__ __forceinline__ f32x4 mfma16(s16x8 a, s16x8 b, f32x4 c) {
  return __builtin_amdgcn_mfma_f32_16x16x32_bf16(
      __builtin_bit_cast(bf16x8, a), __builtin_bit_cast(bf16x8, b), c, 0, 0, 0);
}

// ---------------------------------------------------------------- kernel 0
// Generic [128][C] fp32 -> [C][128] bf16 transpose, 64-col stripes per block.
// blocks 0..63 -> Wo (C=4096); 64,65 -> Wq; 66,67 -> Wk; 68,69 -> Wv (C=128).
__global__ __launch_bounds__(256) void k0_prep(
    const float* __restrict__ Wq, const float* __restrict__ Wk,
    const float* __restrict__ Wv, const float* __restrict__ Wo,
    unsigned short* __restrict__ WqkvT, unsigned short* __restrict__ WoT)
{
  __shared__ alignas(16) short sT[64][136];   // [col][row], 272B row stride (16B-mult)
  const int b = blockIdx.x;
  const float* in; unsigned short* out; int C; int n0;
  if (b < 64)      { in = Wo; out = WoT;           C = 4096; n0 = b << 6; }
  else if (b < 66) { in = Wq; out = WqkvT;         C = 128;  n0 = (b - 64) << 6; }
  else if (b < 68) { in = Wk; out = WqkvT + 16384; C = 128;  n0 = (b - 66) << 6; }
  else             { in = Wv; out = WqkvT + 32768; C = 128;  n0 = (b - 68) << 6; }
  const int t  = threadIdx.x;
  const int rr = t >> 4;          // 0..15
  const int c4 = (t & 15) << 2;   // 0..60
  #pragma unroll
  for (int i = 0; i < 8; ++i) {
    int r = i * 16 + rr;
    float4 v = *(const float4*)(in + r * C + n0 + c4);   // coalesced
    sT[c4 + 0][r] = f2bf(v.x);
    sT[c4 + 1][r] = f2bf(v.y);
    sT[c4 + 2][r] = f2bf(v.z);
    sT[c4 + 3][r] = f2bf(v.w);
  }
  __syncthreads();
  const int c  = t >> 2;          // 0..63
  const int k0 = (t & 3) << 5;    // 0,32,64,96
  #pragma unroll
  for (int j = 0; j < 4; ++j)     // coalesced 16B writes
    *(s16x8*)&out[(n0 + c) * 128 + k0 + j * 8] = *(const s16x8*)&sT[c][k0 + j * 8];
}

// ---------------------------------------------------------------- kernel 1
// grid (128 graphs, 4 heads), 64 threads (one wave).
__global__ __launch_bounds__(64) void k1_qkv_attn(
    const float* __restrict__ nodes,
    const unsigned short* __restrict__ WqkvT,   // [3][n=h*32+c][d]
    const float* __restrict__ bq, const float* __restrict__ bk,
    const float* __restrict__ bv,
    unsigned short* __restrict__ attout)
{
  const int g = blockIdx.x;
  const int h = blockIdx.y;
  const int lane = threadIdx.x;
  const int l15 = lane & 15;
  const int qd = lane >> 4;

  __shared__ alignas(16) short sN[32][136];   // nodes_g bf16, padded
  __shared__ alignas(16) short sQ[32][40];    // q[m][c] (pre-scaled by 1/sqrt(32))
  __shared__ alignas(16) short sK[32][40];    // k[m'][c]
  __shared__ alignas(16) short sVT[32][40];   // v^T[n][m]
  __shared__ alignas(16) short sP[32][40];    // softmax probs [m][m']

  // ---- stage nodes (fp32 -> bf16)
  const float* ng = nodes + g * 32 * 128;
  #pragma unroll
  for (int i = 0; i < 16; ++i) {
    int f4  = i * 64 + lane;
    int row = f4 >> 5;
    int c4  = (f4 & 31) << 2;
    float4 v = *(const float4*)(ng + row * 128 + c4);
    s16x4 p;
    p[0] = f2bf(v.x); p[1] = f2bf(v.y); p[2] = f2bf(v.z); p[3] = f2bf(v.w);
    *(s16x4*)&sN[row][c4] = p;
  }
  __syncthreads();

  // A-fragments of nodes (shared by q/k/v)
  s16x8 afrag[2][4];
  #pragma unroll
  for (int mt = 0; mt < 2; ++mt)
    #pragma unroll
    for (int kk = 0; kk < 4; ++kk)
      afrag[mt][kk] = *(const s16x8*)&sN[mt * 16 + l15][kk * 32 + qd * 8];

  const float* Bm[3] = {bq, bk, bv};

  // ---- QKV projections via MFMA (M=32,N=32,K=128 per head)
  #pragma unroll
  for (int m3 = 0; m3 < 3; ++m3) {
    const unsigned short* WT = WqkvT + m3 * 16384;
    // preload all 8 B-fragments: contiguous s16x8, L2-hot
    s16x8 bfr[4][2];
    #pragma unroll
    for (int kk = 0; kk < 4; ++kk)
      #pragma unroll
      for (int nt = 0; nt < 2; ++nt)
        bfr[kk][nt] = *(const s16x8*)&WT[(h * 32 + nt * 16 + l15) * 128 + kk * 32 + qd * 8];
    f32x4 acc[2][2];
    f32x4 zero = {0.f, 0.f, 0.f, 0.f};
    acc[0][0] = zero; acc[0][1] = zero; acc[1][0] = zero; acc[1][1] = zero;
    #pragma unroll
    for (int kk = 0; kk < 4; ++kk)
      #pragma unroll
      for (int mt = 0; mt < 2; ++mt)
        #pragma unroll
        for (int nt = 0; nt < 2; ++nt)
          acc[mt][nt] = mfma16(afrag[mt][kk], bfr[kk][nt], acc[mt][nt]);
    float b0 = Bm[m3][h * 32 + l15];
    float b1 = Bm[m3][h * 32 + 16 + l15];
    #pragma unroll
    for (int mt = 0; mt < 2; ++mt)
      #pragma unroll
      for (int nt = 0; nt < 2; ++nt) {
        float bb = nt ? b1 : b0;
        #pragma unroll
        for (int r = 0; r < 4; ++r) {
          int m = mt * 16 + qd * 4 + r;       // C/D: row=quad*4+reg
          int c = nt * 16 + l15;              //      col=lane&15
          float val = acc[mt][nt][r] + bb;
          if (m3 == 0)      sQ[m][c]  = f2bf(val * 0.17677669529663687f); // 1/sqrt(32)
          else if (m3 == 1) sK[m][c]  = f2bf(val);
          else              sVT[c][m] = f2bf(val);   // transposed for PV B-operand
        }
      }
  }
  __syncthreads();

  // ---- scores = q @ k^T  (M=32,N=32,K=32 -> 4 MFMA)
  s16x8 qf[2], kf[2];
  #pragma unroll
  for (int mt = 0; mt < 2; ++mt) qf[mt] = *(const s16x8*)&sQ[mt * 16 + l15][qd * 8];
  #pragma unroll
  for (int nt = 0; nt < 2; ++nt) kf[nt] = *(const s16x8*)&sK[nt * 16 + l15][qd * 8];
  f32x4 sacc[2][2];
  {
    f32x4 zero = {0.f, 0.f, 0.f, 0.f};
    #pragma unroll
    for (int mt = 0; mt < 2; ++mt)
      #pragma unroll
      for (int nt = 0; nt < 2; ++nt)
        sacc[mt][nt] = mfma16(qf[mt], kf[nt], zero);
  }

  // ---- softmax over 32 cols
  #pragma unroll
  for (int mt = 0; mt < 2; ++mt)
    #pragma unroll
    for (int r = 0; r < 4; ++r) {
      float a0 = sacc[mt][0][r], a1 = sacc[mt][1][r];
      float mx = fmaxf(a0, a1);
      mx = fmaxf(mx, __shfl_xor(mx, 1, 64));
      mx = fmaxf(mx, __shfl_xor(mx, 2, 64));
      mx = fmaxf(mx, __shfl_xor(mx, 4, 64));
      mx = fmaxf(mx, __shfl_xor(mx, 8, 64));
      float e0 = __expf(a0 - mx), e1 = __expf(a1 - mx);
      float s = e0 + e1;
      s += __shfl_xor(s, 1, 64);
      s += __shfl_xor(s, 2, 64);
      s += __shfl_xor(s, 4, 64);
      s += __shfl_xor(s, 8, 64);
      float inv = 1.0f / s;
      int m = mt * 16 + qd * 4 + r;
      sP[m][l15]      = f2bf(e0 * inv);
      sP[m][16 + l15] = f2bf(e1 * inv);
    }
  __syncthreads();

  // ---- out = P @ v  (4 MFMA), write attout bf16
  s16x8 pf[2], vf[2];
  #pragma unroll
  for (int mt = 0; mt < 2; ++mt) pf[mt] = *(const s16x8*)&sP[mt * 16 + l15][qd * 8];
  #pragma unroll
  for (int nt = 0; nt < 2; ++nt) vf[nt] = *(const s16x8*)&sVT[nt * 16 + l15][qd * 8];
  f32x4 oacc[2][2];
  {
    f32x4 zero = {0.f, 0.f, 0.f, 0.f};
    #pragma unroll
    for (int mt = 0; mt < 2; ++mt)
      #pragma unroll
      for (int nt = 0; nt < 2; ++nt)
        oacc[mt][nt] = mfma16(pf[mt], vf[nt], zero);
  }
  unsigned short* ao = attout + (g * 32) * 128 + h * 32;
  #pragma unroll
  for (int mt = 0; mt < 2; ++mt)
    #pragma unroll
    for (int nt = 0; nt < 2; ++nt)
      #pragma unroll
      for (int r = 0; r < 4; ++r) {
        int m = mt * 16 + qd * 4 + r;
        int c = nt * 16 + l15;
        ao[m * 128 + c] = (unsigned short)f2bf(oacc[mt][nt][r]);
      }
}

// ---------------------------------------------------------------- kernel 3
// C[4096][4096] = attout[4096][128] @ Wo[128][4096] + bo. 128x128 tiles, K=128 whole.
__global__ __launch_bounds__(256) void k3_gemm(
    const unsigned short* __restrict__ A,   // attout bf16 [4096][128]
    const unsigned short* __restrict__ BT,  // WoT bf16 [4096 n][128 k]
    const float* __restrict__ bo,
    float* __restrict__ C)
{
  __shared__ alignas(16) short sA[128][136];
  __shared__ alignas(16) short sB[128][136];
  const int t  = threadIdx.x;
  const int m0 = blockIdx.y << 7;
  const int n0 = blockIdx.x << 7;

  #pragma unroll
  for (int i = 0; i < 8; ++i) {
    int id  = i * 256 + t;
    int row = id >> 4;
    int ch  = (id & 15) << 3;
    *(s16x8*)&sA[row][ch] = *(const s16x8*)(A  + (m0 + row) * 128 + ch);
    *(s16x8*)&sB[row][ch] = *(const s16x8*)(BT + (n0 + row) * 128 + ch);
  }
  __syncthreads();

  const int w    = t >> 6;
  const int lane = t & 63;
  const int l15  = lane & 15;
  const int qd   = lane >> 4;
  const int wm   = (w >> 1) << 6;
  const int wn   = (w & 1) << 6;

  f32x4 acc[4][4];
  {
    f32x4 zero = {0.f, 0.f, 0.f, 0.f};
    #pragma unroll
    for (int i = 0; i < 4; ++i)
      #pragma unroll
      for (int j = 0; j < 4; ++j) acc[i][j] = zero;
  }

  #pragma unroll
  for (int kk = 0; kk < 4; ++kk) {
    s16x8 af[4], bf[4];
    #pragma unroll
    for (int i = 0; i < 4; ++i)
      af[i] = *(const s16x8*)&sA[wm + i * 16 + l15][kk * 32 + qd * 8];
    #pragma unroll
    for (int j = 0; j < 4; ++j)
      bf[j] = *(const s16x8*)&sB[wn + j * 16 + l15][kk * 32 + qd * 8];
    #pragma unroll
    for (int i = 0; i < 4; ++i)
      #pragma unroll
      for (int j = 0; j < 4; ++j)
        acc[i][j] = mfma16(af[i], bf[j], acc[i][j]);
  }

  float bov[4];
  #pragma unroll
  for (int j = 0; j < 4; ++j) bov[j] = bo[n0 + wn + j * 16 + l15];

  #pragma unroll
  for (int i = 0; i < 4; ++i) {
    int rbase = m0 + wm + i * 16 + qd * 4;
    #pragma unroll
    for (int r = 0; r < 4; ++r) {
      float* crow = C + (rbase + r) * 4096 + n0 + wn + l15;
      #pragma unroll
      for (int j = 0; j < 4; ++j)
        crow[j * 16] = acc[i][j][r] + bov[j];
    }
  }
}

// ---------------------------------------------------------------- launch
extern "C" void kernel_launch(void* const* d_in, const int* in_sizes, int n_in,
                              void* d_out, int out_size, void* d_ws, size_t ws_size,
                              hipStream_t stream) {
  const float* nodes = (const float*)d_in[0];
  // d_in[1] = n_node (always 32 per graph) — segmentation hard-coded
  const float* Wq = (const float*)d_in[2];
  const float* bq = (const float*)d_in[3];
  const float* Wk = (const float*)d_in[4];
  const float* bk = (const float*)d_in[5];
  const float* Wv = (const float*)d_in[6];
  const float* bv = (const float*)d_in[7];
  const float* Wo = (const float*)d_in[8];
  const float* bo = (const float*)d_in[9];
  float* out = (float*)d_out;

  unsigned short* attout = (unsigned short*)d_ws;          // 4096*128 bf16
  unsigned short* WoT    = attout + 4096 * 128;            // 4096*128 bf16
  unsigned short* WqkvT  = WoT + 4096 * 128;               // 3*128*128 bf16

  k0_prep<<<70, 256, 0, stream>>>(Wq, Wk, Wv, Wo, WqkvT, WoT);
  k1_qkv_attn<<<dim3(128, 4), 64, 0, stream>>>(nodes, WqkvT, bq, bk, bv, attout);
  k3_gemm<<<dim3(32, 32), 256, 0, stream>>>(attout, WoT, bo, out);
}